// Round 19
// baseline (107.028 us; speedup 1.0000x reference)
//
#include <hip/hip_runtime.h>

#define DM 768
#define NH 12
#define DH 64
#define BB 8
#define SS 1024
#define BS (BB*SS)      /* 8192 */
#define QKVN (3*DM)     /* 2304 */

typedef __attribute__((ext_vector_type(8)))  __bf16 bf16x8;
typedef __attribute__((ext_vector_type(4)))  __bf16 bf16x4;
typedef __attribute__((ext_vector_type(4)))  float  f32x4;
typedef __attribute__((ext_vector_type(16))) float  f32x16;

__device__ __forceinline__ unsigned short f2bf(float f){
  union { float f; unsigned u; } v; v.f = f;
  unsigned r = v.u + 0x7FFFu + ((v.u >> 16) & 1u);
  return (unsigned short)(r >> 16);
}

__device__ __forceinline__ f32x4 mfma_bf16(bf16x8 a, bf16x8 b, f32x4 c){
  return __builtin_amdgcn_mfma_f32_16x16x32_bf16(a, b, c, 0, 0, 0);
}
__device__ __forceinline__ f32x16 mfma32(bf16x8 a, bf16x8 b, f32x16 c){
  return __builtin_amdgcn_mfma_f32_32x32x16_bf16(a, b, c, 0, 0, 0);
}

// async global->LDS, 16B per lane. LDS dest must be wave-uniform base + lane*16.
__device__ __forceinline__ void lds16(const unsigned short* g, unsigned short* l){
  __builtin_amdgcn_global_load_lds(
      (const __attribute__((address_space(1))) void*)g,
      (__attribute__((address_space(3))) void*)l, 16, 0, 0);
}

// ---------------- fused prep kernel: cvt + W_QKV transpose + W_O transpose ----------------
// blocks [0,432): W_Q/K/V transpose  [12][768][64] -> [3][12][64][768]
// blocks [432,576): W_O transpose    [768][768] -> [768][768]^T
// blocks [576,1600): x fp32 -> bf16  (grid-stride over 1.57M float4)

__global__ __launch_bounds__(256, 4)
void k_prep(const float* __restrict__ x, const float* __restrict__ wq,
            const float* __restrict__ wk, const float* __restrict__ wv,
            const float* __restrict__ wo,
            unsigned short* __restrict__ xbf, unsigned short* __restrict__ wqkvt,
            unsigned short* __restrict__ wot){
  __shared__ float t[64][65];
  const int q = blockIdx.x;
  if (q < 432){
    // W_QKV transpose: z = q/12 in [0,36), ry = q%12
    const int z = q / 12, ry = q % 12;
    const int sel = z / 12, hh = z % 12;
    const int r0 = ry * 64;
    const float* src = (sel == 0 ? wq : sel == 1 ? wk : wv) + (size_t)hh*DM*DH;
    unsigned short* d = wqkvt + (size_t)sel*DM*DM + (size_t)hh*DH*DM;
    int tx = threadIdx.x & 63, ty = threadIdx.x >> 6;
    #pragma unroll
    for (int r = ty; r < 64; r += 4)
      t[r][tx] = src[(size_t)(r0 + r)*DH + tx];
    __syncthreads();
    #pragma unroll
    for (int cc = ty; cc < 64; cc += 4)
      d[(size_t)cc*DM + r0 + tx] = f2bf(t[tx][cc]);
  } else if (q < 576){
    // W_O transpose: p = q-432 in [0,144): bx = p%12, by = p/12
    const int p = q - 432;
    const int c0 = (p % 12) * 64, r0 = (p / 12) * 64;
    int tx = threadIdx.x & 63, ty = threadIdx.x >> 6;
    #pragma unroll
    for (int r = ty; r < 64; r += 4)
      t[r][tx] = wo[(size_t)(r0 + r)*DM + c0 + tx];
    __syncthreads();
    #pragma unroll
    for (int cc = ty; cc < 64; cc += 4)
      wot[(size_t)(c0 + cc)*DM + r0 + tx] = f2bf(t[tx][cc]);
  } else {
    // x cvt: 1024 blocks grid-stride over n4 = BS*DM/4 float4 groups
    const int n4 = (BS*DM)/4;
    int i = (q - 576)*256 + threadIdx.x;
    const int stride = 1024*256;
    for (; i < n4; i += stride){
      float4 f = reinterpret_cast<const float4*>(x)[i];
      ushort4 u;
      u.x = f2bf(f.x); u.y = f2bf(f.y); u.z = f2bf(f.z); u.w = f2bf(f.w);
      reinterpret_cast<ushort4*>(xbf)[i] = u;
    }
  }
}

// ---------------- QKV GEMM: 128x192 tile, BK=32, dbuf + counted vmcnt, 768 blocks = 3/CU --
// X[8192][768] * Wqkv_t[2304][768]^T. LDS 40KB total (2 buffers of 20KB) -> 3 co-resident
// blocks/CU preserved; dbuf + vmcnt(5) keeps stage(t+1)'s 5 loads in flight across the
// barrier, hidden under compute(t) — stage latency no longer on the per-step critical path.
// 24 K-steps, 5 lds16/thread/step (A:2 B:3), XOR swizzle over 4 chunks (ch ^ (row&3)).
// XCD map: g&7 -> 1024-row M-strip x all N (X 1.5MB + W 3.5MB ~ L2-resident per XCD).

__global__ __launch_bounds__(256, 2)
void k_gemm_qkv(const unsigned short* __restrict__ X, const unsigned short* __restrict__ Wt,
    const float* __restrict__ bQ, const float* __restrict__ bK, const float* __restrict__ bV,
    unsigned short* __restrict__ Qo, unsigned short* __restrict__ Ko, unsigned short* __restrict__ Vo){
  __shared__ __align__(16) unsigned short lA[2][128*32];
  __shared__ __align__(16) unsigned short lB[2][192*32];
  const int g = blockIdx.x;
  const int xcd = g & 7, idx = g >> 3;     // idx in [0,96)
  const int bx = idx % 12, yy = idx / 12;  // 12 N-tiles, 8 M-tiles per XCD strip
  const int brow = (xcd*8 + yy)*128;
  const int bcol = bx*192;
  const int tid = threadIdx.x, lane = tid & 63, wid = tid >> 6;
  const int wr = wid >> 1, wc = wid & 1;   // 2M x 2N waves, per-wave 64x96
  f32x4 acc[4][6];
  #pragma unroll
  for (int m=0;m<4;m++)
    #pragma unroll
    for (int n=0;n<6;n++) acc[m][n] = (f32x4){0.f,0.f,0.f,0.f};

  // stage one BK=32 K-slab (A: 512 slots, B: 768 slots of 8 bf16) into buffer BUF
  #define QKV_STG(T, BUF) do {                                                     \
    const int k0_ = (T)*32;                                                        \
    _Pragma("unroll")                                                              \
    for (int q=0;q<2;q++){                                                         \
      int flat = q*256 + tid;                                                      \
      int row = flat >> 2, ch = flat & 3, sch = ch ^ (row & 3);                    \
      lds16(X + (size_t)(brow+row)*DM + k0_ + sch*8, lA[BUF] + (size_t)flat*8);    \
    }                                                                              \
    _Pragma("unroll")                                                              \
    for (int q=0;q<3;q++){                                                         \
      int flat = q*256 + tid;                                                      \
      int row = flat >> 2, ch = flat & 3, sch = ch ^ (row & 3);                    \
      lds16(Wt + (size_t)(bcol+row)*DM + k0_ + sch*8, lB[BUF] + (size_t)flat*8);   \
    }                                                                              \
  } while(0)

  QKV_STG(0, 0);
  asm volatile("s_waitcnt vmcnt(0)" ::: "memory");
  __builtin_amdgcn_s_barrier();
  for (int t=0; t<24; ++t){
    if (t+1 < 24){
      if ((t+1)&1) QKV_STG(t+1, 1); else QKV_STG(t+1, 0);
      asm volatile("s_waitcnt vmcnt(5)" ::: "memory");   // stage(t) done; t+1's 5 in flight
    } else {
      asm volatile("s_waitcnt vmcnt(0)" ::: "memory");
    }
    __builtin_amdgcn_s_barrier();      // buffer t ready for all waves
    const unsigned short* cA = lA[t&1];
    const unsigned short* cB = lB[t&1];
    const int cp = lane >> 4;          // k-chunk 0..3 within BK=32
    bf16x8 af[4], bfr[6];
    #pragma unroll
    for (int m=0;m<4;m++){
      int row = wr*64 + m*16 + (lane&15);
      af[m] = *reinterpret_cast<const bf16x8*>(cA + row*32 + ((cp ^ (row&3))<<3));
    }
    #pragma unroll
    for (int n=0;n<6;n++){
      int row = wc*96 + n*16 + (lane&15);
      bfr[n] = *reinterpret_cast<const bf16x8*>(cB + row*32 + ((cp ^ (row&3))<<3));
    }
    __builtin_amdgcn_s_setprio(1);
    #pragma unroll
    for (int m=0;m<4;m++)
      #pragma unroll
      for (int n=0;n<6;n++)
        acc[m][n] = mfma_bf16(af[m], bfr[n], acc[m][n]);
    __builtin_amdgcn_s_setprio(0);
    __builtin_amdgcn_s_barrier();      // all waves done reading buf t before t+2 overwrites
  }
  #undef QKV_STG

  // epilogue: Q scaled 1/8, V stored transposed [bh][d][s]
  #pragma unroll
  for (int m=0;m<4;m++){
    int r = brow + wr*64 + m*16 + ((lane>>4)<<2);
    int b = r >> 10, s = r & 1023;
    #pragma unroll
    for (int n=0;n<6;n++){
      int c = bcol + wc*96 + n*16 + (lane&15);
      int sel = c / DM;
      int hd = c - sel*DM;
      int h = hd >> 6, d = hd & 63;
      if (sel == 0){
        float bias = bQ[hd];
        unsigned short* dst = Qo + ((size_t)(b*NH + h)*SS + s)*DH + d;
        #pragma unroll
        for (int j=0;j<4;j++) dst[(size_t)j*DH] = f2bf((acc[m][n][j] + bias) * 0.125f);
      } else if (sel == 1){
        float bias = bK[hd];
        unsigned short* dst = Ko + ((size_t)(b*NH + h)*SS + s)*DH + d;
        #pragma unroll
        for (int j=0;j<4;j++) dst[(size_t)j*DH] = f2bf(acc[m][n][j] + bias);
      } else {
        float bias = bV[hd];
        unsigned short* dst = Vo + ((size_t)(b*NH + h)*DH + d)*SS + s;  // V^T
        #pragma unroll
        for (int j=0;j<4;j++) dst[j] = f2bf(acc[m][n][j] + bias);
      }
    }
  }
}

// ------- 128x128 GEMM core (R8-proven: dbuf + T2 swizzle + one __syncthreads/K-step) -------

__device__ __forceinline__ void gemm_stage(const unsigned short* __restrict__ A,
    const unsigned short* __restrict__ Bt, int Kd, int brow, int bcol, int k0,
    unsigned short* lA, unsigned short* lB, int tid){
  #pragma unroll
  for (int q=0;q<4;q++){
    int flat = q*256 + tid;            // 0..1023 : 128 rows x 8 chunks of 8 bf16
    int row = flat >> 3, ch = flat & 7;
    int sch = ch ^ (row & 7);          // pre-swizzled global source
    lds16(A  + (size_t)(brow+row)*Kd + k0 + sch*8, lA + (size_t)flat*8);
    lds16(Bt + (size_t)(bcol+row)*Kd + k0 + sch*8, lB + (size_t)flat*8);
  }
}

__device__ __forceinline__ void gemm_compute(const unsigned short* lA, const unsigned short* lB,
    f32x4 acc[4][4], int lane, int wr, int wc){
  #pragma unroll
  for (int kk=0;kk<2;kk++){
    bf16x8 af[4], bfr[4];
    const int cp = kk*4 + (lane>>4);
    #pragma unroll
    for (int m=0;m<4;m++){
      int row = wr*64 + m*16 + (lane&15);
      af[m] = *reinterpret_cast<const bf16x8*>(lA + row*64 + ((cp ^ (row&7))<<3));
    }
    #pragma unroll
    for (int n=0;n<4;n++){
      int row = wc*64 + n*16 + (lane&15);
      bfr[n] = *reinterpret_cast<const bf16x8*>(lB + row*64 + ((cp ^ (row&7))<<3));
    }
    #pragma unroll
    for (int m=0;m<4;m++)
      #pragma unroll
      for (int n=0;n<4;n++)
        acc[m][n] = mfma_bf16(af[m], bfr[n], acc[m][n]);
  }
}

__device__ __forceinline__ void gemm_core(const unsigned short* __restrict__ A,
    const unsigned short* __restrict__ Bt, int Kd, int brow, int bcol,
    unsigned short* lA0, unsigned short* lB0, unsigned short* lA1, unsigned short* lB1,
    f32x4 acc[4][4], int lane, int wr, int wc){
  const int tid = threadIdx.x;
  #pragma unroll
  for (int m=0;m<4;m++)
    #pragma unroll
    for (int n=0;n<4;n++) acc[m][n] = (f32x4){0.f,0.f,0.f,0.f};
  const int nk = Kd / 64;
  gemm_stage(A, Bt, Kd, brow, bcol, 0, lA0, lB0, tid);
  __syncthreads();
  for (int t=0; t<nk; ++t){
    unsigned short* cA = (t&1) ? lA1 : lA0;
    unsigned short* cB = (t&1) ? lB1 : lB0;
    unsigned short* nA = (t&1) ? lA0 : lA1;
    unsigned short* nB = (t&1) ? lB0 : lB1;
    if (t+1 < nk)
      gemm_stage(A, Bt, Kd, brow, bcol, (t+1)*64, nA, nB, tid);  // prefetch BEFORE compute
    gemm_compute(cA, cB, acc, lane, wr, wc);
    __syncthreads();                    // one vmcnt(0)+barrier per K-step
  }
}

// Output GEMM: Z[8192][768] * Wo_t[768][768]^T + b_O -> fp32 out  (exact R8 version)
__global__ __launch_bounds__(256, 2)
void k_gemm_out(const unsigned short* __restrict__ Z, const unsigned short* __restrict__ Wot,
    const float* __restrict__ bO, float* __restrict__ Out){
  __shared__ __align__(16) unsigned short lA[2][128*64];
  __shared__ __align__(16) unsigned short lB[2][128*64];
  const int bcol = blockIdx.x*128, brow = blockIdx.y*128;
  const int tid = threadIdx.x, lane = tid & 63, wid = tid >> 6;
  const int wr = wid >> 1, wc = wid & 1;
  f32x4 acc[4][4];
  gemm_core(Z, Wot, DM, brow, bcol, lA[0], lB[0], lA[1], lB[1], acc, lane, wr, wc);
  #pragma unroll
  for (int m=0;m<4;m++){
    int r = brow + wr*64 + m*16 + ((lane>>4)<<2);
    #pragma unroll
    for (int n=0;n<4;n++){
      int c = bcol + wc*64 + n*16 + (lane&15);
      float bias = bO[c];
      float* dst = Out + (size_t)r*DM + c;
      #pragma unroll
      for (int j=0;j<4;j++) dst[(size_t)j*DM] = acc[m][n][j] + bias;
    }
  }
}

// ---------------- flash attention (causal, swapped-QK^T in-register softmax) ----------------
// (exact R17 version: CU-load-balanced (bh,t) map + in-register softmax)

__device__ __forceinline__ void attn_stage(const unsigned short* __restrict__ Kb,
    const unsigned short* __restrict__ Vb, int kv0,
    unsigned short* kd, unsigned short* vd, int tid){
  #pragma unroll
  for (int qq=0; qq<2; qq++){
    int flat = qq*256 + tid;           // 0..511 : 64 rows x 8 chunks of 8 bf16
    int row = flat >> 3, ch = flat & 7;
    int sch = ch ^ (row & 7);          // pre-swizzled global source, linear LDS dest
    lds16(Kb + (size_t)(kv0+row)*DH + sch*8, kd + (size_t)flat*8);
    lds16(Vb + (size_t)row*SS + kv0 + sch*8, vd + (size_t)flat*8);
  }
}

#define PVSTEP(PA, C) do {                                                        \
  _Pragma("unroll")                                                               \
  for (int h8=0; h8<2; ++h8){                                                     \
    const int ch0 = (C)*4 + h8*2;                                                 \
    union { bf16x4 h[2]; bf16x8 v; } u0, u1;                                      \
    u0.h[0] = *reinterpret_cast<const bf16x4*>(vc + l31*64      + (((ch0  ) ^ swz)<<3) + hi*4); \
    u0.h[1] = *reinterpret_cast<const bf16x4*>(vc + l31*64      + (((ch0+1) ^ swz)<<3) + hi*4); \
    u1.h[0] = *reinterpret_cast<const bf16x4*>(vc + (l31+32)*64 + (((ch0  ) ^ swz)<<3) + hi*4); \
    u1.h[1] = *reinterpret_cast<const bf16x4*>(vc + (l31+32)*64 + (((ch0+1) ^ swz)<<3) + hi*4); \
    o0 = mfma32(PA[h8], u0.v, o0);                                                \
    o1 = mfma32(PA[h8], u1.v, o1);                                                \
  }                                                                               \
} while(0)

__device__ __forceinline__ void attn_tile32(const unsigned short* kc, const unsigned short* vc,
    const bf16x8 qf[4], float* scw, int l31, int hi, int qlane, int qminw, int kv0,
    f32x16& o0, f32x16& o1, float& m, float& l){
  // S^T[kv 64][q 32] : two 32-kv tiles (A = K rows, B = Q)
  f32x16 s0 = (f32x16)0.f, s1 = (f32x16)0.f;
  const int swz = l31 & 7;
  __builtin_amdgcn_s_setprio(1);
  #pragma unroll
  for (int ks=0; ks<4; ++ks){
    const int cp = ks*2 + hi;
    bf16x8 k0 = *reinterpret_cast<const bf16x8*>(kc + l31*64      + ((cp ^ swz)<<3));
    bf16x8 k1 = *reinterpret_cast<const bf16x8*>(kc + (l31+32)*64 + ((cp ^ swz)<<3));
    s0 = mfma32(k0, qf[ks], s0);
    s1 = mfma32(k1, qf[ks], s1);
  }
  __builtin_amdgcn_s_setprio(0);
  // causal mask (diagonal tiles only): kv = kv0 + c*32 + (r&3)+8*(r>>2)+4*hi
  if (kv0 + 64 > qminw){
    #pragma unroll
    for (int r=0;r<16;++r){
      int kvr = kv0 + (r&3) + 8*(r>>2) + hi*4;
      s0[r] = (kvr      > qlane) ? -1e30f : s0[r];
      s1[r] = (kvr + 32 > qlane) ? -1e30f : s1[r];
    }
  }
  // row max: in-register tree + one cross-half shuffle
  float t0=-1e30f, t1=-1e30f, t2=-1e30f, t3=-1e30f;
  #pragma unroll
  for (int r=0;r<16;r+=4){
    t0 = fmaxf(t0, fmaxf(s0[r],   s1[r]));
    t1 = fmaxf(t1, fmaxf(s0[r+1], s1[r+1]));
    t2 = fmaxf(t2, fmaxf(s0[r+2], s1[r+2]));
    t3 = fmaxf(t3, fmaxf(s0[r+3], s1[r+3]));
  }
  float pmax = fmaxf(fmaxf(t0,t1), fmaxf(t2,t3));
  const float pfull = fmaxf(pmax, __shfl_xor(pmax, 32, 64));
  // defer-max (T13): rescale only when max jumps by >8
  if (!__all(pfull - m <= 8.0f)){
    float mn = fmaxf(m, pfull);
    float sc = __expf(m - mn);
    m = mn;
    l *= sc;
    if (hi == 0) scw[l31] = sc;        // per-q sc, broadcast to O lanes
    #pragma unroll
    for (int r=0;r<16;++r){
      float scr = scw[(r&3) + 8*(r>>2) + hi*4];
      o0[r] *= scr; o1[r] *= scr;
    }
  }
  // P = exp(S - m), row sum
  #pragma unroll
  for (int r=0;r<16;++r){
    s0[r] = __expf(s0[r] - m);
    s1[r] = __expf(s1[r] - m);
  }
  float a0=0.f, a1=0.f, a2=0.f, a3=0.f;
  #pragma unroll
  for (int r=0;r<16;r+=4){
    a0 += s0[r]   + s1[r];
    a1 += s0[r+1] + s1[r+1];
    a2 += s0[r+2] + s1[r+2];
    a3 += s0[r+3] + s1[r+3];
  }
  float rsum = (a0+a1) + (a2+a3);
  l += rsum + __shfl_xor(rsum, 32, 64);
  // P -> bf16 A-fragments IN PLACE (lane keeps its own registers; compiler-fused cvt)
  bf16x8 pa0[2], pa1[2];
  #pragma unroll
  for (int h8=0; h8<2; ++h8){
    #pragma unroll
    for (int j=0; j<8; ++j){
      pa0[h8][j] = (__bf16)s0[h8*8 + j];
      pa1[h8][j] = (__bf16)s1[h8*8 + j];
    }
  }
  // PV: O[q][d] += P * V ; V B-slots read to match P's natural kv mapping
  __builtin_amdgcn_s_setprio(1);
  PVSTEP(pa0, 0);
  PVSTEP(pa1, 1);
  __builtin_amdgcn_s_setprio(0);
}

__global__ __launch_bounds__(256, 3)
void k_attn(const unsigned short* __restrict__ Qp, const unsigned short* __restrict__ Kp,
            const unsigned short* __restrict__ Vp, unsigned short* __restrict__ Zp){
  __shared__ __align__(16) unsigned short kl[2][64*64];
  __shared__ __align__(16) unsigned short vl[2][64*64];
  __shared__ float scl[4][32];
  const int g = blockIdx.x;
  const int xcd = g & 7, r = g >> 3;   // r in [0,96)
  // balanced (bh, t) mapping: dw = dispatch wave, a = CU-slot class, bq_ = bh sub-index
  const int dw = r >> 5;               // 0..2
  const int c  = r & 31;
  const int a  = c & 7, bq_ = c >> 3;  // a: 0..7, bq_: 0..3
  int t;
  if (dw == 0)      t = a;
  else if (dw == 1) t = (a + 3) & 7;
  else              t = (0x13502467u >> (a << 2)) & 7;   // T2 = [7,6,4,2,0,5,3,1]
  const int bh = xcd + 8*(bq_ + 4*dw); // bh grouped per XCD (12 bh per XCD, K/V in L2)
  const int kvn = 2*(t + 1);           // kv tiles of 64
  const int tid = threadIdx.x;
  const int lane = tid & 63;
  const int w = tid >> 6;              // 4 waves x 32 q-rows
  const int l31 = lane & 31;
  const int hi = lane >> 5;
  const int qminw = t*128 + w*32;
  const int qlane = qminw + l31;
  const unsigned short* Qb = Qp + (size_t)bh * (SS*DH);
  const unsigned short* Kb = Kp + (size_t)bh * (SS*DH);
  const unsigned short* Vb = Vp + (size_t)bh * (DH*SS);

  // hoist Q B-fragments: lane holds q-row qlane, d-chunk ks*16 + hi*8 (pre-scaled 1/8)
  bf16x8 qf[4];
  #pragma unroll
  for (int ks=0; ks<4; ++ks)
    qf[ks] = *reinterpret_cast<const bf16x8*>(Qb + (size_t)qlane*DH + ks*16 + hi*8);

  f32x16 o0 = (f32x16)0.f, o1 = (f32x16)0.f;   // O: col(lane&31)=d-tile 0/1, row=q-local
  float m = -1e30f, l = 0.f;

  attn_stage(Kb, Vb, 0, kl[0], vl[0], tid);
  __syncthreads();
  for (int s = 0; s < kvn; ++s){
    int cur = s & 1;
    if (s + 1 < kvn)
      attn_stage(Kb, Vb, (s+1)*64, kl[cur^1], vl[cur^1], tid);
    if (s*64 <= qminw + 31)            // wave has >=1 unmasked column in this kv tile
      attn_tile32(kl[cur], vl[cur], qf, scl[w], l31, hi, qlane, qminw, s*64, o0, o1, m, l);
    __syncthreads();
  }

  // normalize and write Z: O row q-local = (r&3)+8*(r>>2)+4*hi (m74 C/D layout)
  if (hi == 0) scl[w][l31] = l;
  const int b = bh / NH, h = bh - b*NH;
  #pragma unroll
  for (int rr=0; rr<16; ++rr){
    const int qloc = (rr&3) + 8*(rr>>2) + hi*4;
    float inv = 1.f / scl[w][qloc];
    unsigned short* zr = Zp + (size_t)(b*SS + qminw + qloc)*DM + h*DH;
    zr[l31]      = f2bf(o0[rr] * inv);
    zr[32 + l31] = f2bf(o1[rr] * inv);
  }
}

// ---------------- launch ----------------

extern "C" void kernel_launch(void* const* d_in, const int* in_sizes, int n_in,
                              void* d_out, int out_size, void* d_ws, size_t ws_size,
                              hipStream_t stream){
  const float* x  = (const float*)d_in[0];
  const float* wq = (const float*)d_in[1];
  const float* wk = (const float*)d_in[2];
  const float* wv = (const float*)d_in[3];
  const float* wo = (const float*)d_in[4];
  const float* bq = (const float*)d_in[5];
  const float* bk = (const float*)d_in[6];
  const float* bv = (const float*)d_in[7];
  const float* bo = (const float*)d_in[8];
  float* out = (float*)d_out;

  char* ws = (char*)d_ws;
  const size_t SZ_X  = (size_t)BS*DM*2;      // 12,582,912
  const size_t SZ_W  = (size_t)QKVN*DM*2;    //  3,538,944
  const size_t SZ_WO = (size_t)DM*DM*2;      //  1,179,648
  unsigned short* xbf   = (unsigned short*)(ws);
  unsigned short* wqkvt = (unsigned short*)(ws + SZ_X);
  unsigned short* wot   = (unsigned short*)(ws + SZ_X + SZ_W);
  unsigned short* Qw    = (unsigned short*)(ws + SZ_X + SZ_W + SZ_WO);
  unsigned short* Kw    = (unsigned short*)(ws + SZ_X + SZ_W + SZ_WO + SZ_X);
  unsigned short* Vw    = (unsigned short*)(ws + SZ_X + SZ_W + SZ_WO + 2*SZ_X);
  unsigned short* Zw    = xbf;               // x consumed by QKV GEMM before attn writes Z

  k_prep<<<dim3(1600), dim3(256), 0, stream>>>(x, wq, wk, wv, wo, xbf, wqkvt, wot);

  k_gemm_qkv<<<dim3(768),              dim3(256), 0, stream>>>(xbf, wqkvt, bq, bk, bv, Qw, Kw, Vw);
  k_attn    <<<dim3(768),              dim3(256), 0, stream>>>(Qw, Kw, Vw, Zw);
  k_gemm_out<<<dim3(DM/128, BS/128),   dim3(256), 0, stream>>>(Zw, wot, bo, out);
}

// Round 20
// 105.673 us; speedup vs baseline: 1.0128x; 1.0128x over previous
//
#include <hip/hip_runtime.h>

#define DM 768
#define NH 12
#define DH 64
#define BB 8
#define SS 1024
#define BS (BB*SS)      /* 8192 */
#define QKVN (3*DM)     /* 2304 */

typedef __attribute__((ext_vector_type(8)))  __bf16 bf16x8;
typedef __attribute__((ext_vector_type(4)))  __bf16 bf16x4;
typedef __attribute__((ext_vector_type(4)))  float  f32x4;
typedef __attribute__((ext_vector_type(16))) float  f32x16;

__device__ __forceinline__ unsigned short f2bf(float f){
  union { float f; unsigned u; } v; v.f = f;
  unsigned r = v.u + 0x7FFFu + ((v.u >> 16) & 1u);
  return (unsigned short)(r >> 16);
}

__device__ __forceinline__ f32x4 mfma_bf16(bf16x8 a, bf16x8 b, f32x4 c){
  return __builtin_amdgcn_mfma_f32_16x16x32_bf16(a, b, c, 0, 0, 0);
}
__device__ __forceinline__ f32x16 mfma32(bf16x8 a, bf16x8 b, f32x16 c){
  return __builtin_amdgcn_mfma_f32_32x32x16_bf16(a, b, c, 0, 0, 0);
}

// async global->LDS, 16B per lane. LDS dest must be wave-uniform base + lane*16.
__device__ __forceinline__ void lds16(const unsigned short* g, unsigned short* l){
  __builtin_amdgcn_global_load_lds(
      (const __attribute__((address_space(1))) void*)g,
      (__attribute__((address_space(3))) void*)l, 16, 0, 0);
}

// ---------------- fused prep kernel: cvt + W_QKV transpose + W_O transpose ----------------
// blocks [0,432): W_Q/K/V transpose  [12][768][64] -> [3][12][64][768]
// blocks [432,576): W_O transpose    [768][768] -> [768][768]^T
// blocks [576,1600): x fp32 -> bf16  (grid-stride over 1.57M float4)

__global__ __launch_bounds__(256, 4)
void k_prep(const float* __restrict__ x, const float* __restrict__ wq,
            const float* __restrict__ wk, const float* __restrict__ wv,
            const float* __restrict__ wo,
            unsigned short* __restrict__ xbf, unsigned short* __restrict__ wqkvt,
            unsigned short* __restrict__ wot){
  __shared__ float t[64][65];
  const int q = blockIdx.x;
  if (q < 432){
    // W_QKV transpose: z = q/12 in [0,36), ry = q%12
    const int z = q / 12, ry = q % 12;
    const int sel = z / 12, hh = z % 12;
    const int r0 = ry * 64;
    const float* src = (sel == 0 ? wq : sel == 1 ? wk : wv) + (size_t)hh*DM*DH;
    unsigned short* d = wqkvt + (size_t)sel*DM*DM + (size_t)hh*DH*DM;
    int tx = threadIdx.x & 63, ty = threadIdx.x >> 6;
    #pragma unroll
    for (int r = ty; r < 64; r += 4)
      t[r][tx] = src[(size_t)(r0 + r)*DH + tx];
    __syncthreads();
    #pragma unroll
    for (int cc = ty; cc < 64; cc += 4)
      d[(size_t)cc*DM + r0 + tx] = f2bf(t[tx][cc]);
  } else if (q < 576){
    // W_O transpose: p = q-432 in [0,144): bx = p%12, by = p/12
    const int p = q - 432;
    const int c0 = (p % 12) * 64, r0 = (p / 12) * 64;
    int tx = threadIdx.x & 63, ty = threadIdx.x >> 6;
    #pragma unroll
    for (int r = ty; r < 64; r += 4)
      t[r][tx] = wo[(size_t)(r0 + r)*DM + c0 + tx];
    __syncthreads();
    #pragma unroll
    for (int cc = ty; cc < 64; cc += 4)
      wot[(size_t)(c0 + cc)*DM + r0 + tx] = f2bf(t[tx][cc]);
  } else {
    // x cvt: 1024 blocks grid-stride over n4 = BS*DM/4 float4 groups
    const int n4 = (BS*DM)/4;
    int i = (q - 576)*256 + threadIdx.x;
    const int stride = 1024*256;
    for (; i < n4; i += stride){
      float4 f = reinterpret_cast<const float4*>(x)[i];
      ushort4 u;
      u.x = f2bf(f.x); u.y = f2bf(f.y); u.z = f2bf(f.z); u.w = f2bf(f.w);
      reinterpret_cast<ushort4*>(xbf)[i] = u;
    }
  }
}

// ---------------- QKV GEMM: 128x192 tile, 256 threads, 768 blocks = EXACTLY 3/CU ----
// (R15/R18-proven: single 40KB LDS buffer + XOR swizzle + m97 loop; 53us measured in the
// 106us best total. Inter-block TLP (3 co-resident blocks/CU) hides the stage drain.)

__global__ __launch_bounds__(256, 2)
void k_gemm_qkv(const unsigned short* __restrict__ X, const unsigned short* __restrict__ Wt,
    const float* __restrict__ bQ, const float* __restrict__ bK, const float* __restrict__ bV,
    unsigned short* __restrict__ Qo, unsigned short* __restrict__ Ko, unsigned short* __restrict__ Vo){
  __shared__ __align__(16) unsigned short lA[128*64];
  __shared__ __align__(16) unsigned short lB[192*64];
  const int g = blockIdx.x;
  const int xcd = g & 7, idx = g >> 3;     // idx in [0,96)
  const int bx = idx % 12, yy = idx / 12;  // 12 N-tiles, 8 M-tiles per XCD strip
  const int brow = (xcd*8 + yy)*128;
  const int bcol = bx*192;
  const int tid = threadIdx.x, lane = tid & 63, wid = tid >> 6;
  const int wr = wid >> 1, wc = wid & 1;   // 2M x 2N waves, per-wave 64x96
  f32x4 acc[4][6];
  #pragma unroll
  for (int m=0;m<4;m++)
    #pragma unroll
    for (int n=0;n<6;n++) acc[m][n] = (f32x4){0.f,0.f,0.f,0.f};

  for (int t=0; t<12; ++t){
    const int k0 = t*64;
    #pragma unroll
    for (int q=0;q<4;q++){
      int flat = q*256 + tid;
      int row = flat >> 3, ch = flat & 7, sch = ch ^ (row & 7);
      lds16(X + (size_t)(brow+row)*DM + k0 + sch*8, lA + (size_t)flat*8);
    }
    #pragma unroll
    for (int q=0;q<6;q++){
      int flat = q*256 + tid;
      int row = flat >> 3, ch = flat & 7, sch = ch ^ (row & 7);
      lds16(Wt + (size_t)(bcol+row)*DM + k0 + sch*8, lB + (size_t)flat*8);
    }
    __syncthreads();                   // drain; other resident blocks compute meanwhile
    #pragma unroll
    for (int kk=0;kk<2;kk++){
      const int cp = kk*4 + (lane>>4);
      bf16x8 af[4], bfr[6];
      #pragma unroll
      for (int m=0;m<4;m++){
        int row = wr*64 + m*16 + (lane&15);
        af[m] = *reinterpret_cast<const bf16x8*>(lA + row*64 + ((cp ^ (row&7))<<3));
      }
      #pragma unroll
      for (int n=0;n<6;n++){
        int row = wc*96 + n*16 + (lane&15);
        bfr[n] = *reinterpret_cast<const bf16x8*>(lB + row*64 + ((cp ^ (row&7))<<3));
      }
      #pragma unroll
      for (int m=0;m<4;m++)
        #pragma unroll
        for (int n=0;n<6;n++)
          acc[m][n] = mfma_bf16(af[m], bfr[n], acc[m][n]);
    }
    __syncthreads();
  }

  // epilogue: Q scaled 1/8, V stored transposed [bh][d][s]
  #pragma unroll
  for (int m=0;m<4;m++){
    int r = brow + wr*64 + m*16 + ((lane>>4)<<2);
    int b = r >> 10, s = r & 1023;
    #pragma unroll
    for (int n=0;n<6;n++){
      int c = bcol + wc*96 + n*16 + (lane&15);
      int sel = c / DM;
      int hd = c - sel*DM;
      int h = hd >> 6, d = hd & 63;
      if (sel == 0){
        float bias = bQ[hd];
        unsigned short* dst = Qo + ((size_t)(b*NH + h)*SS + s)*DH + d;
        #pragma unroll
        for (int j=0;j<4;j++) dst[(size_t)j*DH] = f2bf((acc[m][n][j] + bias) * 0.125f);
      } else if (sel == 1){
        float bias = bK[hd];
        unsigned short* dst = Ko + ((size_t)(b*NH + h)*SS + s)*DH + d;
        #pragma unroll
        for (int j=0;j<4;j++) dst[(size_t)j*DH] = f2bf(acc[m][n][j] + bias);
      } else {
        float bias = bV[hd];
        unsigned short* dst = Vo + ((size_t)(b*NH + h)*DH + d)*SS + s;  // V^T
        #pragma unroll
        for (int j=0;j<4;j++) dst[j] = f2bf(acc[m][n][j] + bias);
      }
    }
  }
}

// ------- 128x128 GEMM core (R8-proven: dbuf + T2 swizzle + one __syncthreads/K-step) -------

__device__ __forceinline__ void gemm_stage(const unsigned short* __restrict__ A,
    const unsigned short* __restrict__ Bt, int Kd, int brow, int bcol, int k0,
    unsigned short* lA, unsigned short* lB, int tid){
  #pragma unroll
  for (int q=0;q<4;q++){
    int flat = q*256 + tid;            // 0..1023 : 128 rows x 8 chunks of 8 bf16
    int row = flat >> 3, ch = flat & 7;
    int sch = ch ^ (row & 7);          // pre-swizzled global source
    lds16(A  + (size_t)(brow+row)*Kd + k0 + sch*8, lA + (size_t)flat*8);
    lds16(Bt + (size_t)(bcol+row)*Kd + k0 + sch*8, lB + (size_t)flat*8);
  }
}

__device__ __forceinline__ void gemm_compute(const unsigned short* lA, const unsigned short* lB,
    f32x4 acc[4][4], int lane, int wr, int wc){
  #pragma unroll
  for (int kk=0;kk<2;kk++){
    bf16x8 af[4], bfr[4];
    const int cp = kk*4 + (lane>>4);
    #pragma unroll
    for (int m=0;m<4;m++){
      int row = wr*64 + m*16 + (lane&15);
      af[m] = *reinterpret_cast<const bf16x8*>(lA + row*64 + ((cp ^ (row&7))<<3));
    }
    #pragma unroll
    for (int n=0;n<4;n++){
      int row = wc*64 + n*16 + (lane&15);
      bfr[n] = *reinterpret_cast<const bf16x8*>(lB + row*64 + ((cp ^ (row&7))<<3));
    }
    #pragma unroll
    for (int m=0;m<4;m++)
      #pragma unroll
      for (int n=0;n<4;n++)
        acc[m][n] = mfma_bf16(af[m], bfr[n], acc[m][n]);
  }
}

__device__ __forceinline__ void gemm_core(const unsigned short* __restrict__ A,
    const unsigned short* __restrict__ Bt, int Kd, int brow, int bcol,
    unsigned short* lA0, unsigned short* lB0, unsigned short* lA1, unsigned short* lB1,
    f32x4 acc[4][4], int lane, int wr, int wc){
  const int tid = threadIdx.x;
  #pragma unroll
  for (int m=0;m<4;m++)
    #pragma unroll
    for (int n=0;n<4;n++) acc[m][n] = (f32x4){0.f,0.f,0.f,0.f};
  const int nk = Kd / 64;
  gemm_stage(A, Bt, Kd, brow, bcol, 0, lA0, lB0, tid);
  __syncthreads();
  for (int t=0; t<nk; ++t){
    unsigned short* cA = (t&1) ? lA1 : lA0;
    unsigned short* cB = (t&1) ? lB1 : lB0;
    unsigned short* nA = (t&1) ? lA0 : lA1;
    unsigned short* nB = (t&1) ? lB0 : lB1;
    if (t+1 < nk)
      gemm_stage(A, Bt, Kd, brow, bcol, (t+1)*64, nA, nB, tid);  // prefetch BEFORE compute
    gemm_compute(cA, cB, acc, lane, wr, wc);
    __syncthreads();                    // one vmcnt(0)+barrier per K-step
  }
}

// Output GEMM: Z[8192][768] * Wo_t[768][768]^T + b_O -> fp32 out  (exact R8 version)
__global__ __launch_bounds__(256, 2)
void k_gemm_out(const unsigned short* __restrict__ Z, const unsigned short* __restrict__ Wot,
    const float* __restrict__ bO, float* __restrict__ Out){
  __shared__ __align__(16) unsigned short lA[2][128*64];
  __shared__ __align__(16) unsigned short lB[2][128*64];
  const int bcol = blockIdx.x*128, brow = blockIdx.y*128;
  const int tid = threadIdx.x, lane = tid & 63, wid = tid >> 6;
  const int wr = wid >> 1, wc = wid & 1;
  f32x4 acc[4][4];
  gemm_core(Z, Wot, DM, brow, bcol, lA[0], lB[0], lA[1], lB[1], acc, lane, wr, wc);
  #pragma unroll
  for (int m=0;m<4;m++){
    int r = brow + wr*64 + m*16 + ((lane>>4)<<2);
    #pragma unroll
    for (int n=0;n<4;n++){
      int c = bcol + wc*64 + n*16 + (lane&15);
      float bias = bO[c];
      float* dst = Out + (size_t)r*DM + c;
      #pragma unroll
      for (int j=0;j<4;j++) dst[(size_t)j*DM] = acc[m][n][j] + bias;
    }
  }
}

// ---------------- flash attention (causal, swapped-QK^T in-register softmax) ----------------
// (exact R17 version: CU-load-balanced (bh,t) map + in-register softmax)

__device__ __forceinline__ void attn_stage(const unsigned short* __restrict__ Kb,
    const unsigned short* __restrict__ Vb, int kv0,
    unsigned short* kd, unsigned short* vd, int tid){
  #pragma unroll
  for (int qq=0; qq<2; qq++){
    int flat = qq*256 + tid;           // 0..511 : 64 rows x 8 chunks of 8 bf16
    int row = flat >> 3, ch = flat & 7;
    int sch = ch ^ (row & 7);          // pre-swizzled global source, linear LDS dest
    lds16(Kb + (size_t)(kv0+row)*DH + sch*8, kd + (size_t)flat*8);
    lds16(Vb + (size_t)row*SS + kv0 + sch*8, vd + (size_t)flat*8);
  }
}

#define PVSTEP(PA, C) do {                                                        \
  _Pragma("unroll")                                                               \
  for (int h8=0; h8<2; ++h8){                                                     \
    const int ch0 = (C)*4 + h8*2;                                                 \
    union { bf16x4 h[2]; bf16x8 v; } u0, u1;                                      \
    u0.h[0] = *reinterpret_cast<const bf16x4*>(vc + l31*64      + (((ch0  ) ^ swz)<<3) + hi*4); \
    u0.h[1] = *reinterpret_cast<const bf16x4*>(vc + l31*64      + (((ch0+1) ^ swz)<<3) + hi*4); \
    u1.h[0] = *reinterpret_cast<const bf16x4*>(vc + (l31+32)*64 + (((ch0  ) ^ swz)<<3) + hi*4); \
    u1.h[1] = *reinterpret_cast<const bf16x4*>(vc + (l31+32)*64 + (((ch0+1) ^ swz)<<3) + hi*4); \
    o0 = mfma32(PA[h8], u0.v, o0);                                                \
    o1 = mfma32(PA[h8], u1.v, o1);                                                \
  }                                                                               \
} while(0)

__device__ __forceinline__ void attn_tile32(const unsigned short* kc, const unsigned short* vc,
    const bf16x8 qf[4], float* scw, int l31, int hi, int qlane, int qminw, int kv0,
    f32x16& o0, f32x16& o1, float& m, float& l){
  // S^T[kv 64][q 32] : two 32-kv tiles (A = K rows, B = Q)
  f32x16 s0 = (f32x16)0.f, s1 = (f32x16)0.f;
  const int swz = l31 & 7;
  __builtin_amdgcn_s_setprio(1);
  #pragma unroll
  for (int ks=0; ks<4; ++ks){
    const int cp = ks*2 + hi;
    bf16x8 k0 = *reinterpret_cast<const bf16x8*>(kc + l31*64      + ((cp ^ swz)<<3));
    bf16x8 k1 = *reinterpret_cast<const bf16x8*>(kc + (l31+32)*64 + ((cp ^ swz)<<3));
    s0 = mfma32(k0, qf[ks], s0);
    s1 = mfma32(k1, qf[ks], s1);
  }
  __builtin_amdgcn_s_setprio(0);
  // causal mask (diagonal tiles only): kv = kv0 + c*32 + (r&3)+8*(r>>2)+4*hi
  if (kv0 + 64 > qminw){
    #pragma unroll
    for (int r=0;r<16;++r){
      int kvr = kv0 + (r&3) + 8*(r>>2) + hi*4;
      s0[r] = (kvr      > qlane) ? -1e30f : s0[r];
      s1[r] = (kvr + 32 > qlane) ? -1e30f : s1[r];
    }
  }
  // row max: in-register tree + one cross-half shuffle
  float t0=-1e30f, t1=-1e30f, t2=-1e30f, t3=-1e30f;
  #pragma unroll
  for (int r=0;r<16;r+=4){
    t0 = fmaxf(t0, fmaxf(s0[r],   s1[r]));
    t1 = fmaxf(t1, fmaxf(s0[r+1], s1[r+1]));
    t2 = fmaxf(t2, fmaxf(s0[r+2], s1[r+2]));
    t3 = fmaxf(t3, fmaxf(s0[r+3], s1[r+3]));
  }
  float pmax = fmaxf(fmaxf(t0,t1), fmaxf(t2,t3));
  const float pfull = fmaxf(pmax, __shfl_xor(pmax, 32, 64));
  // defer-max (T13): rescale only when max jumps by >8
  if (!__all(pfull - m <= 8.0f)){
    float mn = fmaxf(m, pfull);
    float sc = __expf(m - mn);
    m = mn;
    l *= sc;
    if (hi == 0) scw[l31] = sc;        // per-q sc, broadcast to O lanes
    #pragma unroll
    for (int r=0;r<16;++r){
      float scr = scw[(r&3) + 8*(r>>2) + hi*4];
      o0[r] *= scr; o1[r] *= scr;
    }
  }
  // P = exp(S - m), row sum
  #pragma unroll
  for (int r=0;r<16;++r){
    s0[r] = __expf(s0[r] - m);
    s1[r] = __expf(s1[r] - m);
  }
  float a0=0.f, a1=0.f, a2=0.f, a3=0.f;
  #pragma unroll
  for (int r=0;r<16;r+=4){
    a0 += s0[r]   + s1[r];
    a1 += s0[r+1] + s1[r+1];
    a2 += s0[r+2] + s1[r+2];
    a3 += s0[r+3] + s1[r+3];
  }
  float rsum = (a0+a1) + (a2+a3);
  l += rsum + __shfl_xor(rsum, 32, 64);
  // P -> bf16 A-fragments IN PLACE (lane keeps its own registers; compiler-fused cvt)
  bf16x8 pa0[2], pa1[2];
  #pragma unroll
  for (int h8=0; h8<2; ++h8){
    #pragma unroll
    for (int j=0; j<8; ++j){
      pa0[h8][j] = (__bf16)s0[h8*8 + j];
      pa1[h8][j] = (__bf16)s1[h8*8 + j];
    }
  }
  // PV: O[q][d] += P * V ; V B-slots read to match P's natural kv mapping
  __builtin_amdgcn_s_setprio(1);
  PVSTEP(pa0, 0);
  PVSTEP(pa1, 1);
  __builtin_amdgcn_s_setprio(0);
}

__global__ __launch_bounds__(256, 3)
void k_attn(const unsigned short* __restrict__ Qp, const unsigned short* __restrict__ Kp,
            const unsigned short* __restrict__ Vp, unsigned short* __restrict__ Zp){
  __shared__ __align__(16) unsigned short kl[2][64*64];
  __shared__ __align__(16) unsigned short vl[2][64*64];
  __shared__ float scl[4][32];
  const int g = blockIdx.x;
  const int xcd = g & 7, r = g >> 3;   // r in [0,96)
  // balanced (bh, t) mapping: dw = dispatch wave, a = CU-slot class, bq_ = bh sub-index
  const int dw = r >> 5;               // 0..2
  const int c  = r & 31;
  const int a  = c & 7, bq_ = c >> 3;  // a: 0..7, bq_: 0..3
  int t;
  if (dw == 0)      t = a;
  else if (dw == 1) t = (a + 3) & 7;
  else              t = (0x13502467u >> (a << 2)) & 7;   // T2 = [7,6,4,2,0,5,3,1]
  const int bh = xcd + 8*(bq_ + 4*dw); // bh grouped per XCD (12 bh per XCD, K/V in L2)
  const int kvn = 2*(t + 1);           // kv tiles of 64
  const int tid = threadIdx.x;
  const int lane = tid & 63;
  const int w = tid >> 6;              // 4 waves x 32 q-rows
  const int l31 = lane & 31;
  const int hi = lane >> 5;
  const int qminw = t*128 + w*32;
  const int qlane = qminw + l31;
  const unsigned short* Qb = Qp + (size_t)bh * (SS*DH);
  const unsigned short* Kb = Kp + (size_t)bh * (SS*DH);
  const unsigned short* Vb = Vp + (size_t)bh * (DH*SS);

  // hoist Q B-fragments: lane holds q-row qlane, d-chunk ks*16 + hi*8 (pre-scaled 1/8)
  bf16x8 qf[4];
  #pragma unroll
  for (int ks=0; ks<4; ++ks)
    qf[ks] = *reinterpret_cast<const bf16x8*>(Qb + (size_t)qlane*DH + ks*16 + hi*8);

  f32x16 o0 = (f32x16)0.f, o1 = (f32x16)0.f;   // O: col(lane&31)=d-tile 0/1, row=q-local
  float m = -1e30f, l = 0.f;

  attn_stage(Kb, Vb, 0, kl[0], vl[0], tid);
  __syncthreads();
  for (int s = 0; s < kvn; ++s){
    int cur = s & 1;
    if (s + 1 < kvn)
      attn_stage(Kb, Vb, (s+1)*64, kl[cur^1], vl[cur^1], tid);
    if (s*64 <= qminw + 31)            // wave has >=1 unmasked column in this kv tile
      attn_tile32(kl[cur], vl[cur], qf, scl[w], l31, hi, qlane, qminw, s*64, o0, o1, m, l);
    __syncthreads();
  }

  // normalize and write Z: O row q-local = (r&3)+8*(r>>2)+4*hi (m74 C/D layout)
  if (hi == 0) scl[w][l31] = l;
  const int b = bh / NH, h = bh - b*NH;
  #pragma unroll
  for (int rr=0; rr<16; ++rr){
    const int qloc = (rr&3) + 8*(rr>>2) + hi*4;
    float inv = 1.f / scl[w][qloc];
    unsigned short* zr = Zp + (size_t)(b*SS + qminw + qloc)*DM + h*DH;
    zr[l31]      = f2bf(o0[rr] * inv);
    zr[32 + l31] = f2bf(o1[rr] * inv);
  }
}

// ---------------- launch ----------------

extern "C" void kernel_launch(void* const* d_in, const int* in_sizes, int n_in,
                              void* d_out, int out_size, void* d_ws, size_t ws_size,
                              hipStream_t stream){
  const float* x  = (const float*)d_in[0];
  const float* wq = (const float*)d_in[1];
  const float* wk = (const float*)d_in[2];
  const float* wv = (const float*)d_in[3];
  const float* wo = (const float*)d_in[4];
  const float* bq = (const float*)d_in[5];
  const float* bk = (const float*)d_in[6];
  const float* bv = (const float*)d_in[7];
  const float* bo = (const float*)d_in[8];
  float* out = (float*)d_out;

  char* ws = (char*)d_ws;
  const size_t SZ_X  = (size_t)BS*DM*2;      // 12,582,912
  const size_t SZ_W  = (size_t)QKVN*DM*2;    //  3,538,944
  const size_t SZ_WO = (size_t)DM*DM*2;      //  1,179,648
  unsigned short* xbf   = (unsigned short*)(ws);
  unsigned short* wqkvt = (unsigned short*)(ws + SZ_X);
  unsigned short* wot   = (unsigned short*)(ws + SZ_X + SZ_W);
  unsigned short* Qw    = (unsigned short*)(ws + SZ_X + SZ_W + SZ_WO);
  unsigned short* Kw    = (unsigned short*)(ws + SZ_X + SZ_W + SZ_WO + SZ_X);
  unsigned short* Vw    = (unsigned short*)(ws + SZ_X + SZ_W + SZ_WO + 2*SZ_X);
  unsigned short* Zw    = xbf;               // x consumed by QKV GEMM before attn writes Z

  k_prep<<<dim3(1600), dim3(256), 0, stream>>>(x, wq, wk, wv, wo, xbf, wqkvt, wot);

  k_gemm_qkv<<<dim3(768),              dim3(256), 0, stream>>>(xbf, wqkvt, bq, bk, bv, Qw, Kw, Vw);
  k_attn    <<<dim3(768),              dim3(256), 0, stream>>>(Qw, Kw, Vw, Zw);
  k_gemm_out<<<dim3(DM/128, BS/128),   dim3(256), 0, stream>>>(Zw, wot, bo, out);
}

// Round 21
// 103.969 us; speedup vs baseline: 1.0294x; 1.0164x over previous
//
#include <hip/hip_runtime.h>

#define DM 768
#define NH 12
#define DH 64
#define BB 8
#define SS 1024
#define BS (BB*SS)      /* 8192 */
#define QKVN (3*DM)     /* 2304 */

typedef __attribute__((ext_vector_type(8)))  __bf16 bf16x8;
typedef __attribute__((ext_vector_type(4)))  __bf16 bf16x4;
typedef __attribute__((ext_vector_type(4)))  float  f32x4;
typedef __attribute__((ext_vector_type(16))) float  f32x16;

__device__ __forceinline__ unsigned short f2bf(float f){
  union { float f; unsigned u; } v; v.f = f;
  unsigned r = v.u + 0x7FFFu + ((v.u >> 16) & 1u);
  return (unsigned short)(r >> 16);
}

__device__ __forceinline__ f32x4 mfma_bf16(bf16x8 a, bf16x8 b, f32x4 c){
  return __builtin_amdgcn_mfma_f32_16x16x32_bf16(a, b, c, 0, 0, 0);
}
__device__ __forceinline__ f32x16 mfma32(bf16x8 a, bf16x8 b, f32x16 c){
  return __builtin_amdgcn_mfma_f32_32x32x16_bf16(a, b, c, 0, 0, 0);
}

// async global->LDS, 16B per lane. LDS dest must be wave-uniform base + lane*16.
__device__ __forceinline__ void lds16(const unsigned short* g, unsigned short* l){
  __builtin_amdgcn_global_load_lds(
      (const __attribute__((address_space(1))) void*)g,
      (__attribute__((address_space(3))) void*)l, 16, 0, 0);
}

// ---------------- fused prep kernel: cvt + W_QKV transpose + W_O transpose ----------------
// blocks [0,432): W_Q/K/V transpose  [12][768][64] -> [3][12][64][768]
// blocks [432,576): W_O transpose    [768][768] -> [768][768]^T
// blocks [576,1600): x fp32 -> bf16  (grid-stride over 1.57M float4)

__global__ __launch_bounds__(256, 4)
void k_prep(const float* __restrict__ x, const float* __restrict__ wq,
            const float* __restrict__ wk, const float* __restrict__ wv,
            const float* __restrict__ wo,
            unsigned short* __restrict__ xbf, unsigned short* __restrict__ wqkvt,
            unsigned short* __restrict__ wot){
  __shared__ float t[64][65];
  const int q = blockIdx.x;
  if (q < 432){
    // W_QKV transpose: z = q/12 in [0,36), ry = q%12
    const int z = q / 12, ry = q % 12;
    const int sel = z / 12, hh = z % 12;
    const int r0 = ry * 64;
    const float* src = (sel == 0 ? wq : sel == 1 ? wk : wv) + (size_t)hh*DM*DH;
    unsigned short* d = wqkvt + (size_t)sel*DM*DM + (size_t)hh*DH*DM;
    int tx = threadIdx.x & 63, ty = threadIdx.x >> 6;
    #pragma unroll
    for (int r = ty; r < 64; r += 4)
      t[r][tx] = src[(size_t)(r0 + r)*DH + tx];
    __syncthreads();
    #pragma unroll
    for (int cc = ty; cc < 64; cc += 4)
      d[(size_t)cc*DM + r0 + tx] = f2bf(t[tx][cc]);
  } else if (q < 576){
    // W_O transpose: p = q-432 in [0,144): bx = p%12, by = p/12
    const int p = q - 432;
    const int c0 = (p % 12) * 64, r0 = (p / 12) * 64;
    int tx = threadIdx.x & 63, ty = threadIdx.x >> 6;
    #pragma unroll
    for (int r = ty; r < 64; r += 4)
      t[r][tx] = wo[(size_t)(r0 + r)*DM + c0 + tx];
    __syncthreads();
    #pragma unroll
    for (int cc = ty; cc < 64; cc += 4)
      wot[(size_t)(c0 + cc)*DM + r0 + tx] = f2bf(t[tx][cc]);
  } else {
    // x cvt: 1024 blocks grid-stride over n4 = BS*DM/4 float4 groups
    const int n4 = (BS*DM)/4;
    int i = (q - 576)*256 + threadIdx.x;
    const int stride = 1024*256;
    for (; i < n4; i += stride){
      float4 f = reinterpret_cast<const float4*>(x)[i];
      ushort4 u;
      u.x = f2bf(f.x); u.y = f2bf(f.y); u.z = f2bf(f.z); u.w = f2bf(f.w);
      reinterpret_cast<ushort4*>(xbf)[i] = u;
    }
  }
}

// ---------------- QKV GEMM: 128x192 tile, 256 threads, 768 blocks = EXACTLY 3/CU ----
// (R15/R18-proven: single 40KB LDS buffer + XOR swizzle + m97 loop. Inter-block TLP
// (3 co-resident blocks/CU) hides the stage drain. V^T stores merged to ushort4.)

__global__ __launch_bounds__(256, 2)
void k_gemm_qkv(const unsigned short* __restrict__ X, const unsigned short* __restrict__ Wt,
    const float* __restrict__ bQ, const float* __restrict__ bK, const float* __restrict__ bV,
    unsigned short* __restrict__ Qo, unsigned short* __restrict__ Ko, unsigned short* __restrict__ Vo){
  __shared__ __align__(16) unsigned short lA[128*64];
  __shared__ __align__(16) unsigned short lB[192*64];
  const int g = blockIdx.x;
  const int xcd = g & 7, idx = g >> 3;     // idx in [0,96)
  const int bx = idx % 12, yy = idx / 12;  // 12 N-tiles, 8 M-tiles per XCD strip
  const int brow = (xcd*8 + yy)*128;
  const int bcol = bx*192;
  const int tid = threadIdx.x, lane = tid & 63, wid = tid >> 6;
  const int wr = wid >> 1, wc = wid & 1;   // 2M x 2N waves, per-wave 64x96
  f32x4 acc[4][6];
  #pragma unroll
  for (int m=0;m<4;m++)
    #pragma unroll
    for (int n=0;n<6;n++) acc[m][n] = (f32x4){0.f,0.f,0.f,0.f};

  for (int t=0; t<12; ++t){
    const int k0 = t*64;
    #pragma unroll
    for (int q=0;q<4;q++){
      int flat = q*256 + tid;
      int row = flat >> 3, ch = flat & 7, sch = ch ^ (row & 7);
      lds16(X + (size_t)(brow+row)*DM + k0 + sch*8, lA + (size_t)flat*8);
    }
    #pragma unroll
    for (int q=0;q<6;q++){
      int flat = q*256 + tid;
      int row = flat >> 3, ch = flat & 7, sch = ch ^ (row & 7);
      lds16(Wt + (size_t)(bcol+row)*DM + k0 + sch*8, lB + (size_t)flat*8);
    }
    __syncthreads();                   // drain; other resident blocks compute meanwhile
    #pragma unroll
    for (int kk=0;kk<2;kk++){
      const int cp = kk*4 + (lane>>4);
      bf16x8 af[4], bfr[6];
      #pragma unroll
      for (int m=0;m<4;m++){
        int row = wr*64 + m*16 + (lane&15);
        af[m] = *reinterpret_cast<const bf16x8*>(lA + row*64 + ((cp ^ (row&7))<<3));
      }
      #pragma unroll
      for (int n=0;n<6;n++){
        int row = wc*96 + n*16 + (lane&15);
        bfr[n] = *reinterpret_cast<const bf16x8*>(lB + row*64 + ((cp ^ (row&7))<<3));
      }
      #pragma unroll
      for (int m=0;m<4;m++)
        #pragma unroll
        for (int n=0;n<6;n++)
          acc[m][n] = mfma_bf16(af[m], bfr[n], acc[m][n]);
    }
    __syncthreads();
  }

  // epilogue: Q scaled 1/8, V stored transposed [bh][d][s] (ushort4-merged stores)
  #pragma unroll
  for (int m=0;m<4;m++){
    int r = brow + wr*64 + m*16 + ((lane>>4)<<2);
    int b = r >> 10, s = r & 1023;
    #pragma unroll
    for (int n=0;n<6;n++){
      int c = bcol + wc*96 + n*16 + (lane&15);
      int sel = c / DM;
      int hd = c - sel*DM;
      int h = hd >> 6, d = hd & 63;
      if (sel == 0){
        float bias = bQ[hd];
        unsigned short* dst = Qo + ((size_t)(b*NH + h)*SS + s)*DH + d;
        #pragma unroll
        for (int j=0;j<4;j++) dst[(size_t)j*DH] = f2bf((acc[m][n][j] + bias) * 0.125f);
      } else if (sel == 1){
        float bias = bK[hd];
        unsigned short* dst = Ko + ((size_t)(b*NH + h)*SS + s)*DH + d;
        #pragma unroll
        for (int j=0;j<4;j++) dst[(size_t)j*DH] = f2bf(acc[m][n][j] + bias);
      } else {
        float bias = bV[hd];
        unsigned short* dst = Vo + ((size_t)(b*NH + h)*DH + d)*SS + s;  // V^T, s%4==0
        ushort4 vv;
        vv.x = f2bf(acc[m][n][0] + bias);
        vv.y = f2bf(acc[m][n][1] + bias);
        vv.z = f2bf(acc[m][n][2] + bias);
        vv.w = f2bf(acc[m][n][3] + bias);
        *reinterpret_cast<ushort4*>(dst) = vv;
      }
    }
  }
}

// ------- 128x128 GEMM core (R8-proven: dbuf + T2 swizzle + one __syncthreads/K-step) -------

__device__ __forceinline__ void gemm_stage(const unsigned short* __restrict__ A,
    const unsigned short* __restrict__ Bt, int Kd, int brow, int bcol, int k0,
    unsigned short* lA, unsigned short* lB, int tid){
  #pragma unroll
  for (int q=0;q<4;q++){
    int flat = q*256 + tid;            // 0..1023 : 128 rows x 8 chunks of 8 bf16
    int row = flat >> 3, ch = flat & 7;
    int sch = ch ^ (row & 7);          // pre-swizzled global source
    lds16(A  + (size_t)(brow+row)*Kd + k0 + sch*8, lA + (size_t)flat*8);
    lds16(Bt + (size_t)(bcol+row)*Kd + k0 + sch*8, lB + (size_t)flat*8);
  }
}

__device__ __forceinline__ void gemm_compute(const unsigned short* lA, const unsigned short* lB,
    f32x4 acc[4][4], int lane, int wr, int wc){
  #pragma unroll
  for (int kk=0;kk<2;kk++){
    bf16x8 af[4], bfr[4];
    const int cp = kk*4 + (lane>>4);
    #pragma unroll
    for (int m=0;m<4;m++){
      int row = wr*64 + m*16 + (lane&15);
      af[m] = *reinterpret_cast<const bf16x8*>(lA + row*64 + ((cp ^ (row&7))<<3));
    }
    #pragma unroll
    for (int n=0;n<4;n++){
      int row = wc*64 + n*16 + (lane&15);
      bfr[n] = *reinterpret_cast<const bf16x8*>(lB + row*64 + ((cp ^ (row&7))<<3));
    }
    #pragma unroll
    for (int m=0;m<4;m++)
      #pragma unroll
      for (int n=0;n<4;n++)
        acc[m][n] = mfma_bf16(af[m], bfr[n], acc[m][n]);
  }
}

__device__ __forceinline__ void gemm_core(const unsigned short* __restrict__ A,
    const unsigned short* __restrict__ Bt, int Kd, int brow, int bcol,
    unsigned short* lA0, unsigned short* lB0, unsigned short* lA1, unsigned short* lB1,
    f32x4 acc[4][4], int lane, int wr, int wc){
  const int tid = threadIdx.x;
  #pragma unroll
  for (int m=0;m<4;m++)
    #pragma unroll
    for (int n=0;n<4;n++) acc[m][n] = (f32x4){0.f,0.f,0.f,0.f};
  const int nk = Kd / 64;
  gemm_stage(A, Bt, Kd, brow, bcol, 0, lA0, lB0, tid);
  __syncthreads();
  for (int t=0; t<nk; ++t){
    unsigned short* cA = (t&1) ? lA1 : lA0;
    unsigned short* cB = (t&1) ? lB1 : lB0;
    unsigned short* nA = (t&1) ? lA0 : lA1;
    unsigned short* nB = (t&1) ? lB0 : lB1;
    if (t+1 < nk)
      gemm_stage(A, Bt, Kd, brow, bcol, (t+1)*64, nA, nB, tid);  // prefetch BEFORE compute
    gemm_compute(cA, cB, acc, lane, wr, wc);
    __syncthreads();                    // one vmcnt(0)+barrier per K-step
  }
}

// Output GEMM: Z[8192][768] * Wo_t[768][768]^T + b_O -> fp32 out.
// 384 blocks 1-D with XCD map (R8-proven): each XCD owns 8 row-panels of Z (1.5MB) +
// the whole Wot (1.2MB) -> L2-resident operands per XCD.
__global__ __launch_bounds__(256, 2)
void k_gemm_out(const unsigned short* __restrict__ Z, const unsigned short* __restrict__ Wot,
    const float* __restrict__ bO, float* __restrict__ Out){
  __shared__ __align__(16) unsigned short lA[2][128*64];
  __shared__ __align__(16) unsigned short lB[2][128*64];
  const int g = blockIdx.x;
  const int xcd = g & 7, idx = g >> 3;   // idx in [0,48)
  const int bx = idx % 6, yy = idx / 6;
  const int bcol = bx*128, brow = (xcd*8 + yy)*128;
  const int tid = threadIdx.x, lane = tid & 63, wid = tid >> 6;
  const int wr = wid >> 1, wc = wid & 1;
  f32x4 acc[4][4];
  gemm_core(Z, Wot, DM, brow, bcol, lA[0], lB[0], lA[1], lB[1], acc, lane, wr, wc);
  #pragma unroll
  for (int m=0;m<4;m++){
    int r = brow + wr*64 + m*16 + ((lane>>4)<<2);
    #pragma unroll
    for (int n=0;n<4;n++){
      int c = bcol + wc*64 + n*16 + (lane&15);
      float bias = bO[c];
      float* dst = Out + (size_t)r*DM + c;
      #pragma unroll
      for (int j=0;j<4;j++) dst[(size_t)j*DM] = acc[m][n][j] + bias;
    }
  }
}

// ---------------- flash attention (causal, swapped-QK^T in-register softmax) ----------------
// (exact R17 version: CU-load-balanced (bh,t) map + in-register softmax)

__device__ __forceinline__ void attn_stage(const unsigned short* __restrict__ Kb,
    const unsigned short* __restrict__ Vb, int kv0,
    unsigned short* kd, unsigned short* vd, int tid){
  #pragma unroll
  for (int qq=0; qq<2; qq++){
    int flat = qq*256 + tid;           // 0..511 : 64 rows x 8 chunks of 8 bf16
    int row = flat >> 3, ch = flat & 7;
    int sch = ch ^ (row & 7);          // pre-swizzled global source, linear LDS dest
    lds16(Kb + (size_t)(kv0+row)*DH + sch*8, kd + (size_t)flat*8);
    lds16(Vb + (size_t)row*SS + kv0 + sch*8, vd + (size_t)flat*8);
  }
}

#define PVSTEP(PA, C) do {                                                        \
  _Pragma("unroll")                                                               \
  for (int h8=0; h8<2; ++h8){                                                     \
    const int ch0 = (C)*4 + h8*2;                                                 \
    union { bf16x4 h[2]; bf16x8 v; } u0, u1;                                      \
    u0.h[0] = *reinterpret_cast<const bf16x4*>(vc + l31*64      + (((ch0  ) ^ swz)<<3) + hi*4); \
    u0.h[1] = *reinterpret_cast<const bf16x4*>(vc + l31*64      + (((ch0+1) ^ swz)<<3) + hi*4); \
    u1.h[0] = *reinterpret_cast<const bf16x4*>(vc + (l31+32)*64 + (((ch0  ) ^ swz)<<3) + hi*4); \
    u1.h[1] = *reinterpret_cast<const bf16x4*>(vc + (l31+32)*64 + (((ch0+1) ^ swz)<<3) + hi*4); \
    o0 = mfma32(PA[h8], u0.v, o0);                                                \
    o1 = mfma32(PA[h8], u1.v, o1);                                                \
  }                                                                               \
} while(0)

__device__ __forceinline__ void attn_tile32(const unsigned short* kc, const unsigned short* vc,
    const bf16x8 qf[4], float* scw, int l31, int hi, int qlane, int qminw, int kv0,
    f32x16& o0, f32x16& o1, float& m, float& l){
  // S^T[kv 64][q 32] : two 32-kv tiles (A = K rows, B = Q)
  f32x16 s0 = (f32x16)0.f, s1 = (f32x16)0.f;
  const int swz = l31 & 7;
  __builtin_amdgcn_s_setprio(1);
  #pragma unroll
  for (int ks=0; ks<4; ++ks){
    const int cp = ks*2 + hi;
    bf16x8 k0 = *reinterpret_cast<const bf16x8*>(kc + l31*64      + ((cp ^ swz)<<3));
    bf16x8 k1 = *reinterpret_cast<const bf16x8*>(kc + (l31+32)*64 + ((cp ^ swz)<<3));
    s0 = mfma32(k0, qf[ks], s0);
    s1 = mfma32(k1, qf[ks], s1);
  }
  __builtin_amdgcn_s_setprio(0);
  // causal mask (diagonal tiles only): kv = kv0 + c*32 + (r&3)+8*(r>>2)+4*hi
  if (kv0 + 64 > qminw){
    #pragma unroll
    for (int r=0;r<16;++r){
      int kvr = kv0 + (r&3) + 8*(r>>2) + hi*4;
      s0[r] = (kvr      > qlane) ? -1e30f : s0[r];
      s1[r] = (kvr + 32 > qlane) ? -1e30f : s1[r];
    }
  }
  // row max: in-register tree + one cross-half shuffle
  float t0=-1e30f, t1=-1e30f, t2=-1e30f, t3=-1e30f;
  #pragma unroll
  for (int r=0;r<16;r+=4){
    t0 = fmaxf(t0, fmaxf(s0[r],   s1[r]));
    t1 = fmaxf(t1, fmaxf(s0[r+1], s1[r+1]));
    t2 = fmaxf(t2, fmaxf(s0[r+2], s1[r+2]));
    t3 = fmaxf(t3, fmaxf(s0[r+3], s1[r+3]));
  }
  float pmax = fmaxf(fmaxf(t0,t1), fmaxf(t2,t3));
  const float pfull = fmaxf(pmax, __shfl_xor(pmax, 32, 64));
  // defer-max (T13): rescale only when max jumps by >8
  if (!__all(pfull - m <= 8.0f)){
    float mn = fmaxf(m, pfull);
    float sc = __expf(m - mn);
    m = mn;
    l *= sc;
    if (hi == 0) scw[l31] = sc;        // per-q sc, broadcast to O lanes
    #pragma unroll
    for (int r=0;r<16;++r){
      float scr = scw[(r&3) + 8*(r>>2) + hi*4];
      o0[r] *= scr; o1[r] *= scr;
    }
  }
  // P = exp(S - m), row sum
  #pragma unroll
  for (int r=0;r<16;++r){
    s0[r] = __expf(s0[r] - m);
    s1[r] = __expf(s1[r] - m);
  }
  float a0=0.f, a1=0.f, a2=0.f, a3=0.f;
  #pragma unroll
  for (int r=0;r<16;r+=4){
    a0 += s0[r]   + s1[r];
    a1 += s0[r+1] + s1[r+1];
    a2 += s0[r+2] + s1[r+2];
    a3 += s0[r+3] + s1[r+3];
  }
  float rsum = (a0+a1) + (a2+a3);
  l += rsum + __shfl_xor(rsum, 32, 64);
  // P -> bf16 A-fragments IN PLACE (lane keeps its own registers; compiler-fused cvt)
  bf16x8 pa0[2], pa1[2];
  #pragma unroll
  for (int h8=0; h8<2; ++h8){
    #pragma unroll
    for (int j=0; j<8; ++j){
      pa0[h8][j] = (__bf16)s0[h8*8 + j];
      pa1[h8][j] = (__bf16)s1[h8*8 + j];
    }
  }
  // PV: O[q][d] += P * V ; V B-slots read to match P's natural kv mapping
  __builtin_amdgcn_s_setprio(1);
  PVSTEP(pa0, 0);
  PVSTEP(pa1, 1);
  __builtin_amdgcn_s_setprio(0);
}

__global__ __launch_bounds__(256, 3)
void k_attn(const unsigned short* __restrict__ Qp, const unsigned short* __restrict__ Kp,
            const unsigned short* __restrict__ Vp, unsigned short* __restrict__ Zp){
  __shared__ __align__(16) unsigned short kl[2][64*64];
  __shared__ __align__(16) unsigned short vl[2][64*64];
  __shared__ float scl[4][32];
  const int g = blockIdx.x;
  const int xcd = g & 7, r = g >> 3;   // r in [0,96)
  // balanced (bh, t) mapping: dw = dispatch wave, a = CU-slot class, bq_ = bh sub-index
  const int dw = r >> 5;               // 0..2
  const int c  = r & 31;
  const int a  = c & 7, bq_ = c >> 3;  // a: 0..7, bq_: 0..3
  int t;
  if (dw == 0)      t = a;
  else if (dw == 1) t = (a + 3) & 7;
  else              t = (0x13502467u >> (a << 2)) & 7;   // T2 = [7,6,4,2,0,5,3,1]
  const int bh = xcd + 8*(bq_ + 4*dw); // bh grouped per XCD (12 bh per XCD, K/V in L2)
  const int kvn = 2*(t + 1);           // kv tiles of 64
  const int tid = threadIdx.x;
  const int lane = tid & 63;
  const int w = tid >> 6;              // 4 waves x 32 q-rows
  const int l31 = lane & 31;
  const int hi = lane >> 5;
  const int qminw = t*128 + w*32;
  const int qlane = qminw + l31;
  const unsigned short* Qb = Qp + (size_t)bh * (SS*DH);
  const unsigned short* Kb = Kp + (size_t)bh * (SS*DH);
  const unsigned short* Vb = Vp + (size_t)bh * (DH*SS);

  // hoist Q B-fragments: lane holds q-row qlane, d-chunk ks*16 + hi*8 (pre-scaled 1/8)
  bf16x8 qf[4];
  #pragma unroll
  for (int ks=0; ks<4; ++ks)
    qf[ks] = *reinterpret_cast<const bf16x8*>(Qb + (size_t)qlane*DH + ks*16 + hi*8);

  f32x16 o0 = (f32x16)0.f, o1 = (f32x16)0.f;   // O: col(lane&31)=d-tile 0/1, row=q-local
  float m = -1e30f, l = 0.f;

  attn_stage(Kb, Vb, 0, kl[0], vl[0], tid);
  __syncthreads();
  for (int s = 0; s < kvn; ++s){
    int cur = s & 1;
    if (s + 1 < kvn)
      attn_stage(Kb, Vb, (s+1)*64, kl[cur^1], vl[cur^1], tid);
    if (s*64 <= qminw + 31)            // wave has >=1 unmasked column in this kv tile
      attn_tile32(kl[cur], vl[cur], qf, scl[w], l31, hi, qlane, qminw, s*64, o0, o1, m, l);
    __syncthreads();
  }

  // normalize and write Z: O row q-local = (r&3)+8*(r>>2)+4*hi (m74 C/D layout)
  if (hi == 0) scl[w][l31] = l;
  const int b = bh / NH, h = bh - b*NH;
  #pragma unroll
  for (int rr=0; rr<16; ++rr){
    const int qloc = (rr&3) + 8*(rr>>2) + hi*4;
    float inv = 1.f / scl[w][qloc];
    unsigned short* zr = Zp + (size_t)(b*SS + qminw + qloc)*DM + h*DH;
    zr[l31]      = f2bf(o0[rr] * inv);
    zr[32 + l31] = f2bf(o1[rr] * inv);
  }
}

// ---------------- launch ----------------

extern "C" void kernel_launch(void* const* d_in, const int* in_sizes, int n_in,
                              void* d_out, int out_size, void* d_ws, size_t ws_size,
                              hipStream_t stream){
  const float* x  = (const float*)d_in[0];
  const float* wq = (const float*)d_in[1];
  const float* wk = (const float*)d_in[2];
  const float* wv = (const float*)d_in[3];
  const float* wo = (const float*)d_in[4];
  const float* bq = (const float*)d_in[5];
  const float* bk = (const float*)d_in[6];
  const float* bv = (const float*)d_in[7];
  const float* bo = (const float*)d_in[8];
  float* out = (float*)d_out;

  char* ws = (char*)d_ws;
  const size_t SZ_X  = (size_t)BS*DM*2;      // 12,582,912
  const size_t SZ_W  = (size_t)QKVN*DM*2;    //  3,538,944
  const size_t SZ_WO = (size_t)DM*DM*2;      //  1,179,648
  unsigned short* xbf   = (unsigned short*)(ws);
  unsigned short* wqkvt = (unsigned short*)(ws + SZ_X);
  unsigned short* wot   = (unsigned short*)(ws + SZ_X + SZ_W);
  unsigned short* Qw    = (unsigned short*)(ws + SZ_X + SZ_W + SZ_WO);
  unsigned short* Kw    = (unsigned short*)(ws + SZ_X + SZ_W + SZ_WO + SZ_X);
  unsigned short* Vw    = (unsigned short*)(ws + SZ_X + SZ_W + SZ_WO + 2*SZ_X);
  unsigned short* Zw    = xbf;               // x consumed by QKV GEMM before attn writes Z

  k_prep<<<dim3(1600), dim3(256), 0, stream>>>(x, wq, wk, wv, wo, xbf, wqkvt, wot);

  k_gemm_qkv<<<dim3(768), dim3(256), 0, stream>>>(xbf, wqkvt, bq, bk, bv, Qw, Kw, Vw);
  k_attn    <<<dim3(768), dim3(256), 0, stream>>>(Qw, Kw, Vw, Zw);
  k_gemm_out<<<dim3(384), dim3(256), 0, stream>>>(Zw, wot, bo, out);
}